// Round 1
// baseline (222.087 us; speedup 1.0000x reference)
//
#include <hip/hip_runtime.h>
#include <hip/hip_bf16.h>
#include <stdint.h>

// Problem constants
#define BB 8
#define SS 2048
#define NEXP 16
#define DIN 1024
#define DOUT 1024

typedef short bf16x8 __attribute__((ext_vector_type(8)));
typedef float floatx4 __attribute__((ext_vector_type(4)));

// fp32 -> bf16 round-to-nearest-even (bit trick; inputs are normal floats)
__device__ __forceinline__ unsigned short f2bf(float f) {
    union { float f; unsigned int u; } v; v.f = f;
    unsigned int u = v.u;
    unsigned int r = u + 0x7FFFu + ((u >> 16) & 1u);
    return (unsigned short)(r >> 16);
}

// async global->LDS, 16B per lane. LDS dest = wave-uniform base + lane*16.
__device__ __forceinline__ void gload16(const void* g, void* l) {
    __builtin_amdgcn_global_load_lds(
        (const __attribute__((address_space(1))) void*)g,
        (__attribute__((address_space(3))) void*)l,
        16, 0, 0);
}

// ---------------------------------------------------------------------------
// Kernel 1 (fused prep) — R4 restructure: UNIFORM blocks + parity stagger.
// Old layout (R3-): 8192 tiny x-convert blocks dispatched first, then 1024
// heavy weight-mix blocks -> the HBM stream (x) and L3 stream (w) ran
// back-to-back, heavy blocks formed the tail (57 us, VALUBusy 7%).
// New layout: 1056 blocks, 256 threads.
//   blocks [0,1024):  each owns 1/1024 of the weight-mix (256 thr x 4 cols)
//                     AND 1/1024 of x-convert (64 KB fp32 -> 32 KB bf16).
//                     Even blocks run x->w, odd blocks w->x, so both memory
//                     levels (HBM for x, L3 for w) are busy at all times.
//   blocks [1024,1056): bias mix (8192 threads).
// Whole grid ~4 blocks/CU -> co-resident from t=0, no dispatch-wave tail.
// ---------------------------------------------------------------------------
__global__ __launch_bounds__(256) void prep_kernel(
    const float* __restrict__ x, const float* __restrict__ p,
    const float* __restrict__ w, const float* __restrict__ bias,
    unsigned short* __restrict__ xb, unsigned short* __restrict__ mw,
    float* __restrict__ mb)
{
    const int tid = threadIdx.x;
    const int blk = blockIdx.x;

    if (blk >= 1024) {                      // ---- bias mix (tiny) ----
        const long t = (long)(blk - 1024) * 256 + tid;    // 0..8191
        const int b = (int)(t >> 10), i = (int)(t & 1023);
        float s = 0.f;
        #pragma unroll
        for (int n = 0; n < NEXP; ++n) s += p[b * NEXP + n] * bias[n * DOUT + i];
        mb[t] = s;
        return;
    }

    __shared__ float sp[BB * NEXP];
    if (tid < BB * NEXP) sp[tid] = p[tid];
    __syncthreads();

    // ---- x convert slice: 4096 float4 per block, lane-contiguous ----
    auto xconv = [&]() {
        const float4* xv = (const float4*)x;
        uint2* xo = (uint2*)xb;
        const int base = blk * 4096 + tid;
        #pragma unroll
        for (int u = 0; u < 16; ++u) {
            float4 v = xv[base + u * 256];          // wave reads 1KB contiguous
            uint2 o;
            o.x = (unsigned)f2bf(v.x) | ((unsigned)f2bf(v.y) << 16);
            o.y = (unsigned)f2bf(v.z) | ((unsigned)f2bf(v.w) << 16);
            xo[base + u * 256] = o;                 // wave writes 512B contiguous
        }
    };

    // ---- weight mix slice: 4 columns per thread, all 8 batches ----
    auto wmix = [&]() {
        const long t  = (long)blk * 256 + tid;      // 0..262143
        const long j4 = t * 4;
        float acc[BB][4];
        #pragma unroll
        for (int b = 0; b < BB; ++b)
            #pragma unroll
            for (int k = 0; k < 4; ++k) acc[b][k] = 0.f;
        #pragma unroll
        for (int n = 0; n < NEXP; ++n) {
            float4 wv = *(const float4*)(w + (long)n * DOUT * DIN + j4);
            #pragma unroll
            for (int b = 0; b < BB; ++b) {
                float pb = sp[b * NEXP + n];
                acc[b][0] += pb * wv.x; acc[b][1] += pb * wv.y;
                acc[b][2] += pb * wv.z; acc[b][3] += pb * wv.w;
            }
        }
        #pragma unroll
        for (int b = 0; b < BB; ++b) {
            uint2 o;
            o.x = (unsigned)f2bf(acc[b][0]) | ((unsigned)f2bf(acc[b][1]) << 16);
            o.y = (unsigned)f2bf(acc[b][2]) | ((unsigned)f2bf(acc[b][3]) << 16);
            *(uint2*)(mw + (long)b * DOUT * DIN + j4) = o;
        }
    };

    if (blk & 1) { wmix(); xconv(); }
    else         { xconv(); wmix(); }
}

// ---------------------------------------------------------------------------
// Kernel 2: batched GEMM  out[b] = x_bf16[b] (S x K) * mixed_w[b]^T + mixed_b[b]
// (unchanged this round — clean attribution of the prep restructure; gemm
//  counters should surface in the next top-5 once prep drops below it)
// R3 structure (block-shared staging, 2 barriers/iter) + FULLY UNROLLED K-loop:
//  - 8 global source base pointers hoisted; per-iter offset 128*t bytes folds
//    into the 13-bit immediate of global_load_lds (max 1920 <= 4095).
//  - all LDS read addresses loop-invariant -> hoisted to VGPRs by LICM.
// Grid = (B, N, M): linear block id % 8 == batch -> per-XCD L2 residency
// (R2: FETCH 139->33 MB). XOR swizzle (group ^ row&7) -> 0 bank conflicts (R3).
// LDS 32 KB -> grid-limited 4 blocks/CU (16 waves).
// ---------------------------------------------------------------------------
__global__ __launch_bounds__(256) void gemm_kernel(
    const unsigned short* __restrict__ xb,   // [B][S][DIN] bf16
    const unsigned short* __restrict__ mw,   // [B][DOUT][DIN] bf16
    const float* __restrict__ mb,            // [B][DOUT] fp32
    float* __restrict__ out)                 // [B][S][DOUT] fp32
{
    __shared__ __align__(16) unsigned short sA[128 * 64];  // 16 KB
    __shared__ __align__(16) unsigned short sB[128 * 64];  // 16 KB

    const int tid  = threadIdx.x;
    const int wave = tid >> 6;
    const int lane = tid & 63;
    const int b    = blockIdx.x;          // batch -> XCD (id % 8 == b)
    const int tileN = blockIdx.y * 128;   // over DOUT
    const int tileM = blockIdx.z * 128;   // over S

    const unsigned short* Ag = xb + (long)b * SS * DIN;
    const unsigned short* Bg = mw + (long)b * DOUT * DIN;

    const int q     = lane >> 4;     // quad 0..3
    const int r16   = lane & 15;
    const int mBase = 64 * (wave >> 1);
    const int nBase = 64 * (wave & 1);

    // staging: each wave owns 4 chunks of 1KB (8 rows x 64 bf16) for A and B
    const int sRow   = lane >> 3;                    // 0..7 row within chunk
    const int sColSw = (((lane & 7) ^ sRow) * 8);    // XOR-swizzled source column

    // hoisted global source bases + LDS destinations (loop-invariant)
    const unsigned short* aSrc[4]; const unsigned short* bSrc[4];
    unsigned short* aDst[4]; unsigned short* bDst[4];
    #pragma unroll
    for (int c = 0; c < 4; ++c) {
        const int chunk = wave * 4 + c;              // 0..15
        const int row   = chunk * 8 + sRow;          // 0..127
        aSrc[c] = Ag + (long)(tileM + row) * DIN + sColSw;
        bSrc[c] = Bg + (long)(tileN + row) * DIN + sColSw;
        aDst[c] = &sA[chunk * 512];
        bDst[c] = &sB[chunk * 512];
    }

    // reader: XOR-swizzled 16B-group offsets for the two kk halves (invariant)
    const int swz  = r16 & 7;
    const int colK0 = ((q)     ^ swz) * 8;           // kk = 0..31  (group q)
    const int colK1 = ((q + 4) ^ swz) * 8;           // kk = 32..63 (group q+4)

    floatx4 acc[4][4];
    #pragma unroll
    for (int mi = 0; mi < 4; ++mi)
        #pragma unroll
        for (int ni = 0; ni < 4; ++ni)
            acc[mi][ni] = (floatx4){0.f, 0.f, 0.f, 0.f};

    #pragma unroll
    for (int t = 0; t < 16; ++t) {                   // k0 = 64*t, fully unrolled
        __syncthreads();   // previous tile's compute done before overwrite
        #pragma unroll
        for (int c = 0; c < 4; ++c) {
            gload16(aSrc[c] + 64 * t, aDst[c]);      // +128*t bytes -> imm offset
            gload16(bSrc[c] + 64 * t, bDst[c]);
        }
        __syncthreads();   // loads visible

        #pragma unroll
        for (int kh = 0; kh < 2; ++kh) {
            const int col = kh ? colK1 : colK0;
            bf16x8 af[4], bfv[4];
            #pragma unroll
            for (int i = 0; i < 4; ++i)
                af[i] = *(const bf16x8*)&sA[(mBase + 16 * i + r16) * 64 + col];
            #pragma unroll
            for (int i = 0; i < 4; ++i)
                bfv[i] = *(const bf16x8*)&sB[(nBase + 16 * i + r16) * 64 + col];
            #pragma unroll
            for (int mi = 0; mi < 4; ++mi)
                #pragma unroll
                for (int ni = 0; ni < 4; ++ni)
                    acc[mi][ni] = __builtin_amdgcn_mfma_f32_16x16x32_bf16(
                        af[mi], bfv[ni], acc[mi][ni], 0, 0, 0);
        }
    }

    // epilogue: C[m][n] = acc + mixed_b[b][n]
    float bv[4];
    #pragma unroll
    for (int ni = 0; ni < 4; ++ni)
        bv[ni] = mb[b * DOUT + tileN + nBase + 16 * ni + r16];

    #pragma unroll
    for (int mi = 0; mi < 4; ++mi) {
        #pragma unroll
        for (int rr = 0; rr < 4; ++rr) {
            const int row = tileM + mBase + 16 * mi + q * 4 + rr;
            float* orow = out + (long)b * SS * DOUT + (long)row * DOUT;
            #pragma unroll
            for (int ni = 0; ni < 4; ++ni)
                orow[tileN + nBase + 16 * ni + r16] = acc[mi][ni][rr] + bv[ni];
        }
    }
}

extern "C" void kernel_launch(void* const* d_in, const int* in_sizes, int n_in,
                              void* d_out, int out_size, void* d_ws, size_t ws_size,
                              hipStream_t stream) {
    const float* x    = (const float*)d_in[0];   // [8,2048,1024]
    const float* p    = (const float*)d_in[1];   // [8,16]
    const float* w    = (const float*)d_in[2];   // [16,1024,1024]
    const float* bias = (const float*)d_in[3];   // [16,1024]
    float* out = (float*)d_out;                  // [8,2048,1024]

    // workspace layout: x_bf16 (32 MiB) | mixed_w bf16 (16 MiB) | mixed_b fp32 (32 KiB)
    unsigned short* xb = (unsigned short*)d_ws;
    unsigned short* mw = (unsigned short*)((char*)d_ws + (size_t)33554432);
    float*          mb = (float*)((char*)d_ws + (size_t)33554432 + 16777216);

    prep_kernel<<<dim3(1056), 256, 0, stream>>>(x, p, w, bias, xb, mw, mb);

    dim3 ggrid(BB, DOUT / 128, SS / 128);        // (8,8,16) = 1024 blocks
    gemm_kernel<<<ggrid, 256, 0, stream>>>(xb, mw, mb, out);
}

// Round 2
// 209.153 us; speedup vs baseline: 1.0618x; 1.0618x over previous
//
#include <hip/hip_runtime.h>
#include <hip/hip_bf16.h>
#include <stdint.h>

// Problem constants
#define BB 8
#define SS 2048
#define NEXP 16
#define DIN 1024
#define DOUT 1024

typedef short bf16x8 __attribute__((ext_vector_type(8)));
typedef float floatx4 __attribute__((ext_vector_type(4)));

// fp32 -> bf16 round-to-nearest-even (bit trick; inputs are normal floats)
__device__ __forceinline__ unsigned short f2bf(float f) {
    union { float f; unsigned int u; } v; v.f = f;
    unsigned int u = v.u;
    unsigned int r = u + 0x7FFFu + ((u >> 16) & 1u);
    return (unsigned short)(r >> 16);
}

// async global->LDS, 16B per lane. LDS dest = wave-uniform base + lane*16.
__device__ __forceinline__ void gload16(const void* g, void* l) {
    __builtin_amdgcn_global_load_lds(
        (const __attribute__((address_space(1))) void*)g,
        (__attribute__((address_space(3))) void*)l,
        16, 0, 0);
}

// ---------------------------------------------------------------------------
// Kernel 1 (fused prep) — R5: latency-bound fix = max TLP + longest-job-first.
// R4 post-mortem: uniform 1056-block layout CUT wave supply (occupancy 33->24%,
// 66 us). Prep is latency/TLP-bound (VALU 6.5%, HBM 1.8 of 6.3 TB/s): the fix
// is concurrency + dispatch order, not instruction count.
// Layout (6176 blocks x 256 thr, heavy blocks FIRST so they never form the tail):
//   [0,2048):    weight mix. 2x more blocks than R0 (2 cols/thread, float2
//                loads, all 8 batches; w still read exactly once; acc = 16 reg).
//   [2048,2080): bias mix (8192 threads).
//   [2080,6176): x convert. 4 float4 loads/thread in flight, wave reads 1KB
//                contiguous per load. ~16K tiny waves pack the drain.
// ---------------------------------------------------------------------------
__global__ __launch_bounds__(256) void prep_kernel(
    const float* __restrict__ x, const float* __restrict__ p,
    const float* __restrict__ w, const float* __restrict__ bias,
    unsigned short* __restrict__ xb, unsigned short* __restrict__ mw,
    float* __restrict__ mb)
{
    const int tid = threadIdx.x;
    const int blk = blockIdx.x;

    if (blk < 2048) {                       // ---- weight mix (heavy, first) ----
        __shared__ float sp[BB * NEXP];
        if (tid < BB * NEXP) sp[tid] = p[tid];
        __syncthreads();
        const long t  = (long)blk * 256 + tid;      // 0..524287
        const long j2 = t * 2;                      // column pair
        float acc[BB][2];
        #pragma unroll
        for (int b = 0; b < BB; ++b) { acc[b][0] = 0.f; acc[b][1] = 0.f; }
        #pragma unroll
        for (int n = 0; n < NEXP; ++n) {
            float2 wv = *(const float2*)(w + (long)n * DOUT * DIN + j2);
            #pragma unroll
            for (int b = 0; b < BB; ++b) {
                float pb = sp[b * NEXP + n];
                acc[b][0] += pb * wv.x; acc[b][1] += pb * wv.y;
            }
        }
        #pragma unroll
        for (int b = 0; b < BB; ++b) {
            unsigned o = (unsigned)f2bf(acc[b][0]) | ((unsigned)f2bf(acc[b][1]) << 16);
            *(unsigned*)(mw + (long)b * DOUT * DIN + j2) = o;
        }
    } else if (blk < 2080) {                // ---- bias mix (tiny) ----
        const long t = (long)(blk - 2048) * 256 + tid;    // 0..8191
        const int b = (int)(t >> 10), i = (int)(t & 1023);
        float s = 0.f;
        #pragma unroll
        for (int n = 0; n < NEXP; ++n) s += p[b * NEXP + n] * bias[n * DOUT + i];
        mb[t] = s;
    } else {                                // ---- x convert (streaming drain) ----
        const int cb = blk - 2080;                  // 0..4095
        const float4* xv = (const float4*)x;
        uint2* xo = (uint2*)xb;
        const int base = cb * 1024 + tid;
        #pragma unroll
        for (int u = 0; u < 4; ++u) {
            float4 v = xv[base + u * 256];          // wave reads 1KB contiguous
            uint2 o;
            o.x = (unsigned)f2bf(v.x) | ((unsigned)f2bf(v.y) << 16);
            o.y = (unsigned)f2bf(v.z) | ((unsigned)f2bf(v.w) << 16);
            xo[base + u * 256] = o;                 // wave writes 512B contiguous
        }
    }
}

// ---------------------------------------------------------------------------
// Kernel 2: batched GEMM  out[b] = x_bf16[b] (S x K) * mixed_w[b]^T + mixed_b[b]
// (unchanged — clean attribution; ~45-48 us by subtraction. Next candidate:
//  256^2 8-phase schedule once prep stops dominating.)
// R3 structure (block-shared staging, 2 barriers/iter) + FULLY UNROLLED K-loop:
//  - 8 global source base pointers hoisted; per-iter offset 128*t bytes folds
//    into the 13-bit immediate of global_load_lds (max 1920 <= 4095).
//  - all LDS read addresses loop-invariant -> hoisted to VGPRs by LICM.
// Grid = (B, N, M): linear block id % 8 == batch -> per-XCD L2 residency
// (R2: FETCH 139->33 MB). XOR swizzle (group ^ row&7) -> 0 bank conflicts (R3).
// LDS 32 KB -> grid-limited 4 blocks/CU (16 waves).
// ---------------------------------------------------------------------------
__global__ __launch_bounds__(256) void gemm_kernel(
    const unsigned short* __restrict__ xb,   // [B][S][DIN] bf16
    const unsigned short* __restrict__ mw,   // [B][DOUT][DIN] bf16
    const float* __restrict__ mb,            // [B][DOUT] fp32
    float* __restrict__ out)                 // [B][S][DOUT] fp32
{
    __shared__ __align__(16) unsigned short sA[128 * 64];  // 16 KB
    __shared__ __align__(16) unsigned short sB[128 * 64];  // 16 KB

    const int tid  = threadIdx.x;
    const int wave = tid >> 6;
    const int lane = tid & 63;
    const int b    = blockIdx.x;          // batch -> XCD (id % 8 == b)
    const int tileN = blockIdx.y * 128;   // over DOUT
    const int tileM = blockIdx.z * 128;   // over S

    const unsigned short* Ag = xb + (long)b * SS * DIN;
    const unsigned short* Bg = mw + (long)b * DOUT * DIN;

    const int q     = lane >> 4;     // quad 0..3
    const int r16   = lane & 15;
    const int mBase = 64 * (wave >> 1);
    const int nBase = 64 * (wave & 1);

    // staging: each wave owns 4 chunks of 1KB (8 rows x 64 bf16) for A and B
    const int sRow   = lane >> 3;                    // 0..7 row within chunk
    const int sColSw = (((lane & 7) ^ sRow) * 8);    // XOR-swizzled source column

    // hoisted global source bases + LDS destinations (loop-invariant)
    const unsigned short* aSrc[4]; const unsigned short* bSrc[4];
    unsigned short* aDst[4]; unsigned short* bDst[4];
    #pragma unroll
    for (int c = 0; c < 4; ++c) {
        const int chunk = wave * 4 + c;              // 0..15
        const int row   = chunk * 8 + sRow;          // 0..127
        aSrc[c] = Ag + (long)(tileM + row) * DIN + sColSw;
        bSrc[c] = Bg + (long)(tileN + row) * DIN + sColSw;
        aDst[c] = &sA[chunk * 512];
        bDst[c] = &sB[chunk * 512];
    }

    // reader: XOR-swizzled 16B-group offsets for the two kk halves (invariant)
    const int swz  = r16 & 7;
    const int colK0 = ((q)     ^ swz) * 8;           // kk = 0..31  (group q)
    const int colK1 = ((q + 4) ^ swz) * 8;           // kk = 32..63 (group q+4)

    floatx4 acc[4][4];
    #pragma unroll
    for (int mi = 0; mi < 4; ++mi)
        #pragma unroll
        for (int ni = 0; ni < 4; ++ni)
            acc[mi][ni] = (floatx4){0.f, 0.f, 0.f, 0.f};

    #pragma unroll
    for (int t = 0; t < 16; ++t) {                   // k0 = 64*t, fully unrolled
        __syncthreads();   // previous tile's compute done before overwrite
        #pragma unroll
        for (int c = 0; c < 4; ++c) {
            gload16(aSrc[c] + 64 * t, aDst[c]);      // +128*t bytes -> imm offset
            gload16(bSrc[c] + 64 * t, bDst[c]);
        }
        __syncthreads();   // loads visible

        #pragma unroll
        for (int kh = 0; kh < 2; ++kh) {
            const int col = kh ? colK1 : colK0;
            bf16x8 af[4], bfv[4];
            #pragma unroll
            for (int i = 0; i < 4; ++i)
                af[i] = *(const bf16x8*)&sA[(mBase + 16 * i + r16) * 64 + col];
            #pragma unroll
            for (int i = 0; i < 4; ++i)
                bfv[i] = *(const bf16x8*)&sB[(nBase + 16 * i + r16) * 64 + col];
            #pragma unroll
            for (int mi = 0; mi < 4; ++mi)
                #pragma unroll
                for (int ni = 0; ni < 4; ++ni)
                    acc[mi][ni] = __builtin_amdgcn_mfma_f32_16x16x32_bf16(
                        af[mi], bfv[ni], acc[mi][ni], 0, 0, 0);
        }
    }

    // epilogue: C[m][n] = acc + mixed_b[b][n]
    float bv[4];
    #pragma unroll
    for (int ni = 0; ni < 4; ++ni)
        bv[ni] = mb[b * DOUT + tileN + nBase + 16 * ni + r16];

    #pragma unroll
    for (int mi = 0; mi < 4; ++mi) {
        #pragma unroll
        for (int rr = 0; rr < 4; ++rr) {
            const int row = tileM + mBase + 16 * mi + q * 4 + rr;
            float* orow = out + (long)b * SS * DOUT + (long)row * DOUT;
            #pragma unroll
            for (int ni = 0; ni < 4; ++ni)
                orow[tileN + nBase + 16 * ni + r16] = acc[mi][ni][rr] + bv[ni];
        }
    }
}

extern "C" void kernel_launch(void* const* d_in, const int* in_sizes, int n_in,
                              void* d_out, int out_size, void* d_ws, size_t ws_size,
                              hipStream_t stream) {
    const float* x    = (const float*)d_in[0];   // [8,2048,1024]
    const float* p    = (const float*)d_in[1];   // [8,16]
    const float* w    = (const float*)d_in[2];   // [16,1024,1024]
    const float* bias = (const float*)d_in[3];   // [16,1024]
    float* out = (float*)d_out;                  // [8,2048,1024]

    // workspace layout: x_bf16 (32 MiB) | mixed_w bf16 (16 MiB) | mixed_b fp32 (32 KiB)
    unsigned short* xb = (unsigned short*)d_ws;
    unsigned short* mw = (unsigned short*)((char*)d_ws + (size_t)33554432);
    float*          mb = (float*)((char*)d_ws + (size_t)33554432 + 16777216);

    prep_kernel<<<dim3(6176), 256, 0, stream>>>(x, p, w, bias, xb, mw, mb);

    dim3 ggrid(BB, DOUT / 128, SS / 128);        // (8,8,16) = 1024 blocks
    gemm_kernel<<<ggrid, 256, 0, stream>>>(xb, mw, mb, out);
}